// Round 1
// baseline (800.468 us; speedup 1.0000x reference)
//
#include <hip/hip_runtime.h>
#include <math.h>

#define Bn 4
#define Cn 128
#define Hn 128
#define Wn 128
#define COn 128
#define HWn (Hn*Wn)        // 16384
#define NPIX (Bn*HWn)      // 65536

// ---------------------------------------------------------------------------
// Kernel 1: offset-predicting conv (3x3, SAME, 128 -> 27 channels).
// 1 thread per output pixel, all 27 output channels in registers.
// Transposed weights staged in LDS in two 64-channel halves (oc padded to 28
// so the 27-wide broadcast reads can vectorize).
// ---------------------------------------------------------------------------
__global__ __launch_bounds__(256) void k_offset_conv(
    const float* __restrict__ x, const float* __restrict__ ow,
    const float* __restrict__ ob, float* __restrict__ offs)
{
    __shared__ __align__(16) float sw[64*9*28];   // 64512 B
    const int tid   = threadIdx.x;
    const int pixel = blockIdx.x * 256 + tid;
    const int b  = pixel >> 14;
    const int hw = pixel & (HWn - 1);
    const int h  = hw >> 7;
    const int w  = hw & (Wn - 1);

    float acc[27];
    #pragma unroll
    for (int oc = 0; oc < 27; ++oc) acc[oc] = ob[oc];

    for (int half = 0; half < 2; ++half) {
        // stage transposed weights, coalesced on the global side:
        // i enumerates (oc, jl) with addr = oc*1152 + half*576 + jl
        for (int i = tid; i < 27*576; i += 256) {
            int oc = i / 576;
            int jl = i % 576;          // cc*9 + tap  (cc in [0,64))
            sw[jl*28 + oc] = ow[oc*1152 + half*576 + jl];
        }
        __syncthreads();
        for (int cc = 0; cc < 64; ++cc) {
            const int c = half*64 + cc;
            const float* xp = x + ((size_t)(b*Cn + c) << 14);
            float xv[9];
            #pragma unroll
            for (int tap = 0; tap < 9; ++tap) {
                int y  = h + tap/3 - 1;
                int xx = w + tap%3 - 1;
                bool ok = (y >= 0) & (y < Hn) & (xx >= 0) & (xx < Wn);
                xv[tap] = ok ? xp[y*Wn + xx] : 0.0f;
            }
            #pragma unroll
            for (int tap = 0; tap < 9; ++tap) {
                const float* swp = &sw[(cc*9 + tap)*28];
                #pragma unroll
                for (int oc = 0; oc < 27; ++oc)
                    acc[oc] = fmaf(xv[tap], swp[oc], acc[oc]);
            }
        }
        __syncthreads();
    }
    float* op = offs + (size_t)pixel * 27;
    #pragma unroll
    for (int oc = 0; oc < 27; ++oc) op[oc] = acc[oc];
}

// ---------------------------------------------------------------------------
// Kernel 2: deformable conv main pass.
// Block = 32 consecutive pixels (same b, same h row) x 256 threads.
// Phase A: per-(pixel,tap) gather metadata (4 indices + 4 combined weights
//          = bilinear * valid * sigmoid(mask)) into LDS, computed once.
// K-loop over c: cooperative gather of a[32][9] tile (padded to 12 floats
//          per row for ds_read_b128), then thread (o, ph) does the rank-9
//          update for 16 pixels with fp32 FMAs.
// ---------------------------------------------------------------------------
__global__ __launch_bounds__(256) void k_deform(
    const float* __restrict__ x, const float* __restrict__ dw,
    const float* __restrict__ db, const float* __restrict__ offs,
    float* __restrict__ out)
{
    __shared__ int4   md_i[32*9];
    __shared__ float4 md_f[32*9];
    __shared__ __align__(16) float a_lds[32*12];

    const int tid  = threadIdx.x;
    const int pix0 = blockIdx.x * 32;
    const int b   = pix0 >> 14;
    const int hw0 = pix0 & (HWn - 1);
    const int h   = hw0 >> 7;
    const int w0  = hw0 & (Wn - 1);

    // ---- Phase A: sampling metadata ----
    for (int i = tid; i < 32*9; i += 256) {
        int p = i / 9, tap = i % 9;
        const float* op = offs + (size_t)(pix0 + p) * 27;
        float dy = op[tap], dx = op[9 + tap], mr = op[18 + tap];
        float m  = 1.0f / (1.0f + __expf(-mr));
        float yf = (float)(h + tap/3 - 1) + dy;
        float xf = (float)(w0 + p + tap%3 - 1) + dx;
        float y0f = floorf(yf), x0f = floorf(xf);
        int   y0  = (int)y0f,  x0  = (int)x0f;
        float wy = yf - y0f, wx = xf - x0f;
        int yi0 = min(max(y0,     0), Hn-1), yi1 = min(max(y0 + 1, 0), Hn-1);
        int xi0 = min(max(x0,     0), Wn-1), xi1 = min(max(x0 + 1, 0), Wn-1);
        bool vy0 = (y0 >= 0)     & (y0 < Hn);
        bool vy1 = (y0 + 1 >= 0) & (y0 + 1 < Hn);
        bool vx0 = (x0 >= 0)     & (x0 < Wn);
        bool vx1 = (x0 + 1 >= 0) & (x0 + 1 < Wn);
        md_i[i] = make_int4(yi0*Wn + xi0, yi0*Wn + xi1, yi1*Wn + xi0, yi1*Wn + xi1);
        md_f[i] = make_float4(m * (1.0f-wy) * (1.0f-wx) * ((vy0 & vx0) ? 1.0f : 0.0f),
                              m * (1.0f-wy) * wx        * ((vy0 & vx1) ? 1.0f : 0.0f),
                              m * wy        * (1.0f-wx) * ((vy1 & vx0) ? 1.0f : 0.0f),
                              m * wy        * wx        * ((vy1 & vx1) ? 1.0f : 0.0f));
    }
    __syncthreads();

    const int o  = tid & 127;
    const int ph = tid >> 7;    // pixel half: 0 -> p 0..15, 1 -> p 16..31
    float acc[16];
    #pragma unroll
    for (int p = 0; p < 16; ++p) acc[p] = 0.0f;

    for (int c = 0; c < Cn; ++c) {
        const float* xp = x + ((size_t)(b*Cn + c) << 14);
        // cooperative gather of the a[32][9] tile
        for (int i = tid; i < 288; i += 256) {
            int4   id = md_i[i];
            float4 wt = md_f[i];
            float a = xp[id.x]*wt.x + xp[id.y]*wt.y + xp[id.z]*wt.z + xp[id.w]*wt.w;
            int p = i / 9, tap = i % 9;
            a_lds[p*12 + tap] = a;
        }
        __syncthreads();

        const float* wrow = dw + (size_t)o*1152 + c*9;
        float wv[9];
        #pragma unroll
        for (int t9 = 0; t9 < 9; ++t9) wv[t9] = wrow[t9];

        #pragma unroll
        for (int p = 0; p < 16; ++p) {
            const float4* ar = (const float4*)&a_lds[(ph*16 + p)*12];
            float4 a0 = ar[0], a1 = ar[1], a2 = ar[2];
            acc[p] = fmaf(a0.x, wv[0], acc[p]);
            acc[p] = fmaf(a0.y, wv[1], acc[p]);
            acc[p] = fmaf(a0.z, wv[2], acc[p]);
            acc[p] = fmaf(a0.w, wv[3], acc[p]);
            acc[p] = fmaf(a1.x, wv[4], acc[p]);
            acc[p] = fmaf(a1.y, wv[5], acc[p]);
            acc[p] = fmaf(a1.z, wv[6], acc[p]);
            acc[p] = fmaf(a1.w, wv[7], acc[p]);
            acc[p] = fmaf(a2.x, wv[8], acc[p]);
        }
        __syncthreads();
    }

    const float bias = db[o];
    float* outp = out + ((size_t)(b*COn + o) << 14) + h*Wn + w0 + ph*16;
    #pragma unroll
    for (int p = 0; p < 16; ++p) outp[p] = acc[p] + bias;
}

extern "C" void kernel_launch(void* const* d_in, const int* in_sizes, int n_in,
                              void* d_out, int out_size, void* d_ws, size_t ws_size,
                              hipStream_t stream) {
    const float* x  = (const float*)d_in[0];
    const float* ow = (const float*)d_in[1];
    const float* ob = (const float*)d_in[2];
    const float* dw = (const float*)d_in[3];
    const float* db = (const float*)d_in[4];
    float* out  = (float*)d_out;
    float* offs = (float*)d_ws;   // 65536 * 27 floats = 7.08 MB

    hipLaunchKernelGGL(k_offset_conv, dim3(NPIX/256), dim3(256), 0, stream,
                       x, ow, ob, offs);
    hipLaunchKernelGGL(k_deform, dim3(NPIX/32), dim3(256), 0, stream,
                       x, dw, db, offs, out);
}

// Round 2
// 370.901 us; speedup vs baseline: 2.1582x; 2.1582x over previous
//
#include <hip/hip_runtime.h>
#include <math.h>

#define Bn 4
#define Cn 128
#define Hn 128
#define Wn 128
#define COn 128
#define HWn (Hn*Wn)        // 16384
#define NPIX (Bn*HWn)      // 65536

typedef __attribute__((ext_vector_type(8))) short bf16x8;
typedef __attribute__((ext_vector_type(4))) float f32x4;

__device__ inline short f2bf(float f) {
    union { float f; unsigned u; } cv; cv.f = f;
    unsigned u = cv.u;
    u += 0x7fffu + ((u >> 16) & 1u);   // round-to-nearest-even
    return (short)(u >> 16);
}

// ---------------------------------------------------------------------------
// Kernel 1: offset-predicting conv (3x3, SAME, 128 -> 27 channels). Unchanged
// from R1 (~50 us). 1 thread/pixel, 27 accumulators, transposed weights in LDS.
// ---------------------------------------------------------------------------
__global__ __launch_bounds__(256) void k_offset_conv(
    const float* __restrict__ x, const float* __restrict__ ow,
    const float* __restrict__ ob, float* __restrict__ offs)
{
    __shared__ __align__(16) float sw[64*9*28];   // 64512 B
    const int tid   = threadIdx.x;
    const int pixel = blockIdx.x * 256 + tid;
    const int b  = pixel >> 14;
    const int hw = pixel & (HWn - 1);
    const int h  = hw >> 7;
    const int w  = hw & (Wn - 1);

    float acc[27];
    #pragma unroll
    for (int oc = 0; oc < 27; ++oc) acc[oc] = ob[oc];

    for (int half = 0; half < 2; ++half) {
        for (int i = tid; i < 27*576; i += 256) {
            int oc = i / 576;
            int jl = i % 576;
            sw[jl*28 + oc] = ow[oc*1152 + half*576 + jl];
        }
        __syncthreads();
        for (int cc = 0; cc < 64; ++cc) {
            const int c = half*64 + cc;
            const float* xp = x + ((size_t)(b*Cn + c) << 14);
            float xv[9];
            #pragma unroll
            for (int tap = 0; tap < 9; ++tap) {
                int y  = h + tap/3 - 1;
                int xx = w + tap%3 - 1;
                bool ok = (y >= 0) & (y < Hn) & (xx >= 0) & (xx < Wn);
                xv[tap] = ok ? xp[y*Wn + xx] : 0.0f;
            }
            #pragma unroll
            for (int tap = 0; tap < 9; ++tap) {
                const float* swp = &sw[(cc*9 + tap)*28];
                #pragma unroll
                for (int oc = 0; oc < 27; ++oc)
                    acc[oc] = fmaf(xv[tap], swp[oc], acc[oc]);
            }
        }
        __syncthreads();
    }
    float* op = offs + (size_t)pixel * 27;
    #pragma unroll
    for (int oc = 0; oc < 27; ++oc) op[oc] = acc[oc];
}

// ---------------------------------------------------------------------------
// Kernel 2: pre-pack deform weights into MFMA A-fragment layout, bf16.
// Frag f = ks*8 + ot holds A[m=oc][k] for oc-tile ot, K-step ks:
//   lane l, elem j  ->  oc = ot*16 + (l&15), k = ks*32 + (l>>4)*8 + j,
//   k = tap*128 + c  ->  dw[oc*1152 + c*9 + tap].
// 288 KB total, L2-resident, read coalesced by k_deform_mfma.
// ---------------------------------------------------------------------------
__global__ __launch_bounds__(64) void k_pack_w(
    const float* __restrict__ dw, short* __restrict__ pw)
{
    const int blk = blockIdx.x;          // 0..287  (ks*8 + ot)
    const int ks  = blk >> 3;
    const int ot  = blk & 7;
    const int l   = threadIdx.x;
    const int oc  = ot*16 + (l & 15);
    const int k0  = ks*32 + (l >> 4)*8;
    bf16x8 fr;
    #pragma unroll
    for (int j = 0; j < 8; ++j) {
        int k = k0 + j;
        int tap = k >> 7;
        int c   = k & 127;
        fr[j] = f2bf(dw[oc*1152 + c*9 + tap]);
    }
    *(bf16x8*)(pw + ((size_t)blk*64 + l)*8) = fr;
}

// ---------------------------------------------------------------------------
// Kernel 3: deformable conv main pass, bf16 MFMA, zero LDS.
// Block = 4 waves; wave owns 16 consecutive pixels (one b,h row segment).
// K order: k = tap*128 + c. Per K-step (one tap, 32 c):
//   lane l gathers its OWN B-fragment: px = l&15, c = cb + (l>>4)*8 + j.
//   Bilinear metadata (4 idx + 4 mask*valid*bilinear wgts) computed once/tap.
//   A-fragments (weights) loaded coalesced from packed global (L2-hot).
// D[m=oc][n=px]: row=(l>>4)*4+r, col=l&15 -> coalesced 64B store runs.
// ---------------------------------------------------------------------------
__global__ __launch_bounds__(256) void k_deform_mfma(
    const float* __restrict__ x, const short* __restrict__ pw,
    const float* __restrict__ db, const float* __restrict__ offs,
    float* __restrict__ out)
{
    const int tid = threadIdx.x;
    const int wid = tid >> 6;
    const int l   = tid & 63;
    const int lm  = l & 15;     // pixel within wave tile / D col
    const int lg  = l >> 4;     // k-group
    const int p   = blockIdx.x*64 + wid*16 + lm;
    const int b   = p >> 14;
    const int hw  = p & (HWn - 1);
    const int h   = hw >> 7;
    const int w   = hw & (Wn - 1);
    const int bC  = b * Cn;

    f32x4 acc[8];
    #pragma unroll
    for (int ot = 0; ot < 8; ++ot) acc[ot] = (f32x4){0.f, 0.f, 0.f, 0.f};

    const float* op  = offs + (size_t)p * 27;
    const int4*  apg = (const int4*)pw;

    #pragma unroll 1
    for (int tap = 0; tap < 9; ++tap) {
        // ---- per-(pixel,tap) bilinear metadata, reused over all 128 c ----
        float dy = op[tap], dx = op[9 + tap], mr = op[18 + tap];
        float m  = 1.0f / (1.0f + __expf(-mr));
        float yf = (float)(h + tap/3 - 1) + dy;
        float xf = (float)(w + tap%3 - 1) + dx;
        float y0f = floorf(yf), x0f = floorf(xf);
        int   y0  = (int)y0f,  x0  = (int)x0f;
        float wy = yf - y0f, wx = xf - x0f;
        int yi0 = min(max(y0,     0), Hn-1), yi1 = min(max(y0 + 1, 0), Hn-1);
        int xi0 = min(max(x0,     0), Wn-1), xi1 = min(max(x0 + 1, 0), Wn-1);
        float vy0 = ((y0 >= 0)     & (y0 < Hn))     ? 1.0f : 0.0f;
        float vy1 = ((y0 + 1 >= 0) & (y0 + 1 < Hn)) ? 1.0f : 0.0f;
        float vx0 = ((x0 >= 0)     & (x0 < Wn))     ? 1.0f : 0.0f;
        float vx1 = ((x0 + 1 >= 0) & (x0 + 1 < Wn)) ? 1.0f : 0.0f;
        const int i0 = yi0*Wn + xi0, i1 = yi0*Wn + xi1;
        const int i2 = yi1*Wn + xi0, i3 = yi1*Wn + xi1;
        const float w0_ = m * (1.0f-wy) * (1.0f-wx) * vy0 * vx0;
        const float w1_ = m * (1.0f-wy) * wx        * vy0 * vx1;
        const float w2_ = m * wy        * (1.0f-wx) * vy1 * vx0;
        const float w3_ = m * wy        * wx        * vy1 * vx1;

        #pragma unroll 1
        for (int cq = 0; cq < 4; ++cq) {
            const int ks = tap*4 + cq;
            // A-fragment loads first (independent, L2-hot, coalesced)
            const int4* ap = apg + (size_t)(ks*8)*64 + l;
            // gather this lane's B-fragment: 8 c-values, 4 corners each
            bf16x8 bfrag;
            #pragma unroll
            for (int j = 0; j < 8; ++j) {
                const unsigned pb = (unsigned)((bC + cq*32 + lg*8 + j) << 14);
                float v = x[pb + i0]*w0_ + x[pb + i1]*w1_
                        + x[pb + i2]*w2_ + x[pb + i3]*w3_;
                bfrag[j] = f2bf(v);
            }
            #pragma unroll
            for (int ot = 0; ot < 8; ++ot) {
                int4 av = ap[ot*64];
                acc[ot] = __builtin_amdgcn_mfma_f32_16x16x32_bf16(
                    __builtin_bit_cast(bf16x8, av), bfrag, acc[ot], 0, 0, 0);
            }
        }
    }

    // ---- epilogue: D row=(lg*4+r)=oc within tile, col=lm=pixel ----
    #pragma unroll
    for (int ot = 0; ot < 8; ++ot) {
        #pragma unroll
        for (int r = 0; r < 4; ++r) {
            int oc = ot*16 + lg*4 + r;
            out[((size_t)(b*COn + oc) << 14) + hw] = acc[ot][r] + db[oc];
        }
    }
}

extern "C" void kernel_launch(void* const* d_in, const int* in_sizes, int n_in,
                              void* d_out, int out_size, void* d_ws, size_t ws_size,
                              hipStream_t stream) {
    const float* x  = (const float*)d_in[0];
    const float* ow = (const float*)d_in[1];
    const float* ob = (const float*)d_in[2];
    const float* dw = (const float*)d_in[3];
    const float* db = (const float*)d_in[4];
    float* out  = (float*)d_out;
    float* offs = (float*)d_ws;                       // 65536*27*4 = 7077888 B
    short* pw   = (short*)((char*)d_ws + 7077888);    // 294912 B, 16B-aligned

    hipLaunchKernelGGL(k_offset_conv, dim3(NPIX/256), dim3(256), 0, stream,
                       x, ow, ob, offs);
    hipLaunchKernelGGL(k_pack_w, dim3(288), dim3(64), 0, stream, dw, pw);
    hipLaunchKernelGGL(k_deform_mfma, dim3(NPIX/64), dim3(256), 0, stream,
                       x, pw, db, offs, out);
}

// Round 3
// 335.893 us; speedup vs baseline: 2.3831x; 1.1042x over previous
//
#include <hip/hip_runtime.h>
#include <math.h>

#define Bn 4
#define Cn 128
#define Hn 128
#define Wn 128
#define COn 128
#define HWn (Hn*Wn)        // 16384
#define NPIX (Bn*HWn)      // 65536

typedef __attribute__((ext_vector_type(8))) short bf16x8;
typedef __attribute__((ext_vector_type(4))) float f32x4;

__device__ inline short f2bf(float f) {
    union { float f; unsigned u; } cv; cv.f = f;
    unsigned u = cv.u;
    u += 0x7fffu + ((u >> 16) & 1u);   // round-to-nearest-even
    return (short)(u >> 16);
}

// ---------------------------------------------------------------------------
// Kernel 1: offset-predicting conv (3x3, SAME, 128 -> 27 channels).
// 1 thread/pixel, 27 accumulators, transposed weights in LDS.
// XCD-chunked swizzle so neighboring blocks (sharing x rows) co-reside per XCD.
// ---------------------------------------------------------------------------
__global__ __launch_bounds__(256) void k_offset_conv(
    const float* __restrict__ x, const float* __restrict__ ow,
    const float* __restrict__ ob, float* __restrict__ offs)
{
    __shared__ __align__(16) float sw[64*9*28];   // 64512 B
    const int tid   = threadIdx.x;
    const int bid   = blockIdx.x;                 // 256 blocks, 256 % 8 == 0
    const int wg    = (bid & 7)*32 + (bid >> 3);  // XCD-chunked (bijective)
    const int pixel = wg * 256 + tid;
    const int b  = pixel >> 14;
    const int hw = pixel & (HWn - 1);
    const int h  = hw >> 7;
    const int w  = hw & (Wn - 1);

    float acc[27];
    #pragma unroll
    for (int oc = 0; oc < 27; ++oc) acc[oc] = ob[oc];

    for (int half = 0; half < 2; ++half) {
        for (int i = tid; i < 27*576; i += 256) {
            int oc = i / 576;
            int jl = i % 576;
            sw[jl*28 + oc] = ow[oc*1152 + half*576 + jl];
        }
        __syncthreads();
        for (int cc = 0; cc < 64; ++cc) {
            const int c = half*64 + cc;
            const float* xp = x + ((size_t)(b*Cn + c) << 14);
            float xv[9];
            #pragma unroll
            for (int tap = 0; tap < 9; ++tap) {
                int y  = h + tap/3 - 1;
                int xx = w + tap%3 - 1;
                bool ok = (y >= 0) & (y < Hn) & (xx >= 0) & (xx < Wn);
                xv[tap] = ok ? xp[y*Wn + xx] : 0.0f;
            }
            #pragma unroll
            for (int tap = 0; tap < 9; ++tap) {
                const float* swp = &sw[(cc*9 + tap)*28];
                #pragma unroll
                for (int oc = 0; oc < 27; ++oc)
                    acc[oc] = fmaf(xv[tap], swp[oc], acc[oc]);
            }
        }
        __syncthreads();
    }
    float* op = offs + (size_t)pixel * 27;
    #pragma unroll
    for (int oc = 0; oc < 27; ++oc) op[oc] = acc[oc];
}

// ---------------------------------------------------------------------------
// Kernel 2: pre-pack deform weights into MFMA A-fragment layout, bf16.
// K permutation: K-step ks = cchunk*9 + tap; within-step kk = (l>>4)*8 + j
//   -> c = cchunk*32 + kk, tap = ks % 9.  (must match k_deform_mfma's B!)
// Frag f = ks*8 + ot: lane l elem j -> oc = ot*16 + (l&15), k = (c, tap).
// ---------------------------------------------------------------------------
__global__ __launch_bounds__(64) void k_pack_w(
    const float* __restrict__ dw, short* __restrict__ pw)
{
    const int blk = blockIdx.x;          // 0..287  (ks*8 + ot)
    const int ks  = blk >> 3;
    const int ot  = blk & 7;
    const int cchunk = ks / 9;
    const int tap    = ks - cchunk*9;
    const int l   = threadIdx.x;
    const int oc  = ot*16 + (l & 15);
    const int kk0 = (l >> 4)*8;
    bf16x8 fr;
    #pragma unroll
    for (int j = 0; j < 8; ++j) {
        int c = cchunk*32 + kk0 + j;
        fr[j] = f2bf(dw[oc*1152 + c*9 + tap]);
    }
    *(bf16x8*)(pw + ((size_t)blk*64 + l)*8) = fr;
}

// ---------------------------------------------------------------------------
// Kernel 3: deformable conv main pass, bf16 MFMA, zero LDS.
// Block = 4 waves; wave owns 16 consecutive pixels. XCD-chunked swizzle.
// Loop: cchunk (4, 32 channels each) outer, tap (9) inner UNROLLED:
//   - the 9 taps of one (px-tile, channel-chunk) neighborhood are revisited
//     within 9 consecutive K-steps -> L1-resident reuse window (~16KB/wave)
//     instead of refetching from HBM once per tap (R2: 566 MB fetched).
//   - bilinear metadata recomputed per cchunk; tap unrolled keeps it in regs.
// ---------------------------------------------------------------------------
__global__ __launch_bounds__(256) void k_deform_mfma(
    const float* __restrict__ x, const short* __restrict__ pw,
    const float* __restrict__ db, const float* __restrict__ offs,
    float* __restrict__ out)
{
    const int tid = threadIdx.x;
    const int wid = tid >> 6;
    const int l   = tid & 63;
    const int lm  = l & 15;     // pixel within wave tile / D col
    const int lg  = l >> 4;     // k-group
    const int bid = blockIdx.x;                   // 1024 blocks, 1024 % 8 == 0
    const int wg  = (bid & 7)*128 + (bid >> 3);   // XCD-chunked (bijective)
    const int p   = wg*64 + wid*16 + lm;
    const int b   = p >> 14;
    const int hw  = p & (HWn - 1);
    const int h   = hw >> 7;
    const int w   = hw & (Wn - 1);
    const int bC  = b * Cn;

    f32x4 acc[8];
    #pragma unroll
    for (int ot = 0; ot < 8; ++ot) acc[ot] = (f32x4){0.f, 0.f, 0.f, 0.f};

    const float* op  = offs + (size_t)p * 27;
    const int4*  apg = (const int4*)pw;

    #pragma unroll 1
    for (int cchunk = 0; cchunk < 4; ++cchunk) {
        #pragma unroll
        for (int tap = 0; tap < 9; ++tap) {
            // ---- bilinear metadata for (px, tap); registers only ----
            float dy = op[tap], dx = op[9 + tap], mr = op[18 + tap];
            float m  = 1.0f / (1.0f + __expf(-mr));
            float yf = (float)(h + tap/3 - 1) + dy;
            float xf = (float)(w + tap%3 - 1) + dx;
            float y0f = floorf(yf), x0f = floorf(xf);
            int   y0  = (int)y0f,  x0  = (int)x0f;
            float wy = yf - y0f, wx = xf - x0f;
            int yi0 = min(max(y0,     0), Hn-1), yi1 = min(max(y0 + 1, 0), Hn-1);
            int xi0 = min(max(x0,     0), Wn-1), xi1 = min(max(x0 + 1, 0), Wn-1);
            float vy0 = ((y0 >= 0)     & (y0 < Hn))     ? 1.0f : 0.0f;
            float vy1 = ((y0 + 1 >= 0) & (y0 + 1 < Hn)) ? 1.0f : 0.0f;
            float vx0 = ((x0 >= 0)     & (x0 < Wn))     ? 1.0f : 0.0f;
            float vx1 = ((x0 + 1 >= 0) & (x0 + 1 < Wn)) ? 1.0f : 0.0f;
            const int i0 = yi0*Wn + xi0, i1 = yi0*Wn + xi1;
            const int i2 = yi1*Wn + xi0, i3 = yi1*Wn + xi1;
            const float w0_ = m * (1.0f-wy) * (1.0f-wx) * vy0 * vx0;
            const float w1_ = m * (1.0f-wy) * wx        * vy0 * vx1;
            const float w2_ = m * wy        * (1.0f-wx) * vy1 * vx0;
            const float w3_ = m * wy        * wx        * vy1 * vx1;

            const int ks = cchunk*9 + tap;
            const int4* ap = apg + (size_t)(ks*8)*64 + l;
            // ---- gather this lane's B-fragment: c = cchunk*32 + lg*8 + j ----
            bf16x8 bfrag;
            #pragma unroll
            for (int j = 0; j < 8; ++j) {
                const unsigned pb = (unsigned)((bC + cchunk*32 + lg*8 + j) << 14);
                float v = x[pb + i0]*w0_ + x[pb + i1]*w1_
                        + x[pb + i2]*w2_ + x[pb + i3]*w3_;
                bfrag[j] = f2bf(v);
            }
            #pragma unroll
            for (int ot = 0; ot < 8; ++ot) {
                int4 av = ap[ot*64];
                acc[ot] = __builtin_amdgcn_mfma_f32_16x16x32_bf16(
                    __builtin_bit_cast(bf16x8, av), bfrag, acc[ot], 0, 0, 0);
            }
        }
    }

    // ---- epilogue: D row=(lg*4+r)=oc within tile, col=lm=pixel ----
    #pragma unroll
    for (int ot = 0; ot < 8; ++ot) {
        #pragma unroll
        for (int r = 0; r < 4; ++r) {
            int oc = ot*16 + lg*4 + r;
            out[((size_t)(b*COn + oc) << 14) + hw] = acc[ot][r] + db[oc];
        }
    }
}

extern "C" void kernel_launch(void* const* d_in, const int* in_sizes, int n_in,
                              void* d_out, int out_size, void* d_ws, size_t ws_size,
                              hipStream_t stream) {
    const float* x  = (const float*)d_in[0];
    const float* ow = (const float*)d_in[1];
    const float* ob = (const float*)d_in[2];
    const float* dw = (const float*)d_in[3];
    const float* db = (const float*)d_in[4];
    float* out  = (float*)d_out;
    float* offs = (float*)d_ws;                       // 65536*27*4 = 7077888 B
    short* pw   = (short*)((char*)d_ws + 7077888);    // 294912 B, 16B-aligned

    hipLaunchKernelGGL(k_offset_conv, dim3(NPIX/256), dim3(256), 0, stream,
                       x, ow, ob, offs);
    hipLaunchKernelGGL(k_pack_w, dim3(288), dim3(64), 0, stream, dw, pw);
    hipLaunchKernelGGL(k_deform_mfma, dim3(NPIX/64), dim3(256), 0, stream,
                       x, pw, db, offs, out);
}

// Round 4
// 137.432 us; speedup vs baseline: 5.8244x; 2.4441x over previous
//
#include <hip/hip_runtime.h>
#include <math.h>

#define Bn 4
#define Cn 128
#define Hn 128
#define Wn 128
#define COn 128
#define HWn (Hn*Wn)        // 16384
#define NPIX (Bn*HWn)      // 65536

typedef __attribute__((ext_vector_type(8))) short bf16x8;
typedef __attribute__((ext_vector_type(4))) float f32x4;

__device__ inline short f2bf(float f) {
    union { float f; unsigned u; } cv; cv.f = f;
    unsigned u = cv.u;
    u += 0x7fffu + ((u >> 16) & 1u);   // round-to-nearest-even
    return (short)(u >> 16);
}
__device__ inline float bflo(unsigned w) {
    union { unsigned u; float f; } cv; cv.u = w << 16; return cv.f;
}
__device__ inline float bfhi(unsigned w) {
    union { unsigned u; float f; } cv; cv.u = w & 0xffff0000u; return cv.f;
}
__device__ inline void async_copy16(const void* g, void* l) {
    __builtin_amdgcn_global_load_lds(
        (const __attribute__((address_space(1))) unsigned int*)g,
        (__attribute__((address_space(3))) unsigned int*)l, 16, 0, 0);
}

// ---------------------------------------------------------------------------
// Kernel 1: NCHW f32 -> NHWC bf16 transpose. Block = one (b,h) row.
// LDS tile [w][c] padded to 130 so both phases are bank-conflict-free.
// ---------------------------------------------------------------------------
__global__ __launch_bounds__(256) void k_transpose(
    const float* __restrict__ x, unsigned short* __restrict__ xt)
{
    __shared__ unsigned short t[Wn][Cn + 2];
    const int tid = threadIdx.x;
    const int bh  = blockIdx.x;          // b*128 + h
    const int b   = bh >> 7, h = bh & 127;
    const float* xp = x + (((size_t)b*Cn) << 14) + h*Wn;  // xp[c*HWn + w]
    for (int i = tid; i < Cn*Wn; i += 256) {
        int c = i >> 7, w = i & 127;
        t[w][c] = (unsigned short)f2bf(xp[(size_t)c*HWn + w]);
    }
    __syncthreads();
    unsigned* xto = (unsigned*)(xt + ((size_t)bh << 7) * Cn);
    for (int j = tid; j < Wn*(Cn/2); j += 256) {
        int w = j >> 6, cp = j & 63;
        xto[(size_t)w*64 + cp] = *(const unsigned*)&t[w][2*cp];
    }
}

// ---------------------------------------------------------------------------
// Kernel 2a: pack deform weights into MFMA A-fragment layout, bf16.
// K-step ks = cchunk*9 + tap; kk = (l>>4)*8 + j -> c = cchunk*32 + kk.
// Frag blob[ks*8 + ot]: lane l elem j -> oc = ot*16 + (l&15).
// ---------------------------------------------------------------------------
__global__ __launch_bounds__(64) void k_pack_w(
    const float* __restrict__ dw, short* __restrict__ pw)
{
    const int blk = blockIdx.x;          // 0..287  (ks*8 + ot)
    const int ks  = blk >> 3;
    const int ot  = blk & 7;
    const int cchunk = ks / 9;
    const int tap    = ks - cchunk*9;
    const int l   = threadIdx.x;
    const int oc  = ot*16 + (l & 15);
    const int kk0 = (l >> 4)*8;
    bf16x8 fr;
    #pragma unroll
    for (int j = 0; j < 8; ++j) {
        int c = cchunk*32 + kk0 + j;
        fr[j] = f2bf(dw[oc*1152 + c*9 + tap]);
    }
    *(bf16x8*)(pw + ((size_t)blk*64 + l)*8) = fr;
}

// ---------------------------------------------------------------------------
// Kernel 2b: pack offset-conv weights (27 oc, padded to 32) the same way.
// Frag blob[ks*2 + ot], ot in {0,1}.
// ---------------------------------------------------------------------------
__global__ __launch_bounds__(64) void k_pack_ow(
    const float* __restrict__ ow, short* __restrict__ pwo)
{
    const int blk = blockIdx.x;          // 0..71  (ks*2 + ot)
    const int ks  = blk >> 1;
    const int ot  = blk & 1;
    const int cchunk = ks / 9;
    const int tap    = ks - cchunk*9;
    const int l   = threadIdx.x;
    const int oc  = ot*16 + (l & 15);
    const int kk0 = (l >> 4)*8;
    bf16x8 fr;
    #pragma unroll
    for (int j = 0; j < 8; ++j) {
        int c = cchunk*32 + kk0 + j;
        fr[j] = (oc < 27) ? f2bf(ow[oc*1152 + c*9 + tap]) : (short)0;
    }
    *(bf16x8*)(pwo + ((size_t)blk*64 + l)*8) = fr;
}

// ---------------------------------------------------------------------------
// Kernel 3: offset-predicting conv via MFMA on NHWC-bf16 x.
// Wave = 16 px; 36 K-steps; B-frag = one raw bf16x8 load + zero mask
// (fixed integer taps, zero padding); A via L1 (tiny, 72 KB total).
// ---------------------------------------------------------------------------
__global__ __launch_bounds__(256) void k_offset_mfma(
    const unsigned short* __restrict__ xt, const short* __restrict__ pwo,
    const float* __restrict__ ob, float* __restrict__ offs)
{
    const int tid = threadIdx.x;
    const int wid = tid >> 6;
    const int l   = tid & 63;
    const int lm  = l & 15;
    const int lg  = l >> 4;
    const int bid = blockIdx.x;                   // 1024 blocks
    const int wg  = (bid & 7)*128 + (bid >> 3);   // XCD-chunked
    const int p   = wg*64 + wid*16 + lm;
    const int b   = p >> 14;
    const int hw  = p & (HWn - 1);
    const int h   = hw >> 7;
    const int w   = hw & (Wn - 1);

    f32x4 acc[2];
    acc[0] = (f32x4){0.f,0.f,0.f,0.f};
    acc[1] = (f32x4){0.f,0.f,0.f,0.f};
    const int4* apg = (const int4*)pwo;

    #pragma unroll 1
    for (int ks = 0; ks < 36; ++ks) {
        const int cchunk = ks / 9;
        const int tap    = ks - cchunk*9;
        const int y  = h + tap/3 - 1;
        const int xx = w + (tap - (tap/3)*3) - 1;
        const bool ok = (y >= 0) & (y < Hn) & (xx >= 0) & (xx < Wn);
        const int yc  = min(max(y, 0), Hn-1);
        const int xc  = min(max(xx, 0), Wn-1);
        int4 v = *(const int4*)(xt + (((size_t)(b*Hn + yc)*Wn + xc) << 7)
                                   + cchunk*32 + lg*8);
        if (!ok) v = make_int4(0,0,0,0);
        const int4* ap = apg + (size_t)(ks*2)*64 + l;
        acc[0] = __builtin_amdgcn_mfma_f32_16x16x32_bf16(
            __builtin_bit_cast(bf16x8, ap[0]), __builtin_bit_cast(bf16x8, v), acc[0], 0, 0, 0);
        acc[1] = __builtin_amdgcn_mfma_f32_16x16x32_bf16(
            __builtin_bit_cast(bf16x8, ap[64]), __builtin_bit_cast(bf16x8, v), acc[1], 0, 0, 0);
    }

    #pragma unroll
    for (int ot = 0; ot < 2; ++ot)
        #pragma unroll
        for (int r = 0; r < 4; ++r) {
            int oc = ot*16 + lg*4 + r;
            if (oc < 27) offs[(size_t)p*27 + oc] = acc[ot][r] + ob[oc];
        }
}

// ---------------------------------------------------------------------------
// Kernel 4: deformable conv main pass.
// NHWC-bf16 gathers (1 dwordx4 per corner per lane), A-fragments staged
// via global_load_lds double-buffer (8KB/K-step, shared by all 4 waves),
// conflict-free ds_read_b128, XCD-chunked swizzle.
// ---------------------------------------------------------------------------
__global__ __launch_bounds__(256) void k_deform_mfma(
    const unsigned short* __restrict__ xt, const char* __restrict__ pw,
    const float* __restrict__ db, const float* __restrict__ offs,
    float* __restrict__ out)
{
    __shared__ __align__(16) char a_lds[2][8192];
    const int tid = threadIdx.x;
    const int wid = tid >> 6;
    const int l   = tid & 63;
    const int lm  = l & 15;
    const int lg  = l >> 4;
    const int bid = blockIdx.x;                   // 1024 blocks
    const int wg  = (bid & 7)*128 + (bid >> 3);   // XCD-chunked
    const int p   = wg*64 + wid*16 + lm;
    const int b   = p >> 14;
    const int hw  = p & (HWn - 1);
    const int h   = hw >> 7;
    const int w   = hw & (Wn - 1);

    f32x4 acc[8];
    #pragma unroll
    for (int ot = 0; ot < 8; ++ot) acc[ot] = (f32x4){0.f,0.f,0.f,0.f};

    const float* op = offs + (size_t)p * 27;
    const int rowbase = b*Hn;

    // stage K-step ks into buffer buf (8KB, 512 x 16B, 2 issues/thread)
    #define STAGE(ks_, buf_) {                                                  \
        const char* g0 = pw + (size_t)(ks_)*8192 + wid*1024 + l*16;             \
        async_copy16(g0,        (void*)&a_lds[buf_][wid*1024]);                 \
        async_copy16(g0 + 4096, (void*)&a_lds[buf_][4096 + wid*1024]);          \
    }

    STAGE(0, 0);
    int cur = 0;

    #pragma unroll 1
    for (int ks = 0; ks < 36; ++ks) {
        const int cchunk = ks / 9;
        const int tap    = ks - cchunk*9;
        __syncthreads();                       // buf[cur] staged for all waves
        if (ks + 1 < 36) STAGE(ks + 1, cur ^ 1);

        // ---- bilinear metadata for (px, tap) ----
        float dy = op[tap], dx = op[9 + tap], mr = op[18 + tap];
        float m  = 1.0f / (1.0f + __expf(-mr));
        float yf = (float)(h + tap/3 - 1) + dy;
        float xf = (float)(w + (tap - (tap/3)*3) - 1) + dx;
        float y0f = floorf(yf), x0f = floorf(xf);
        int   y0  = (int)y0f,  x0  = (int)x0f;
        float wy = yf - y0f, wx = xf - x0f;
        int yi0 = min(max(y0,     0), Hn-1), yi1 = min(max(y0 + 1, 0), Hn-1);
        int xi0 = min(max(x0,     0), Wn-1), xi1 = min(max(x0 + 1, 0), Wn-1);
        float vy0 = ((y0 >= 0)     & (y0 < Hn))     ? 1.0f : 0.0f;
        float vy1 = ((y0 + 1 >= 0) & (y0 + 1 < Hn)) ? 1.0f : 0.0f;
        float vx0 = ((x0 >= 0)     & (x0 < Wn))     ? 1.0f : 0.0f;
        float vx1 = ((x0 + 1 >= 0) & (x0 + 1 < Wn)) ? 1.0f : 0.0f;
        const float w0_ = m * (1.0f-wy) * (1.0f-wx) * vy0 * vx0;
        const float w1_ = m * (1.0f-wy) * wx        * vy0 * vx1;
        const float w2_ = m * wy        * (1.0f-wx) * vy1 * vx0;
        const float w3_ = m * wy        * wx        * vy1 * vx1;

        // ---- 4 corner loads: channel-contiguous bf16x8 each ----
        const int cb = cchunk*32 + lg*8;
        const uint4 q0 = *(const uint4*)(xt + (((size_t)((rowbase + yi0)*Wn + xi0)) << 7) + cb);
        const uint4 q1 = *(const uint4*)(xt + (((size_t)((rowbase + yi0)*Wn + xi1)) << 7) + cb);
        const uint4 q2 = *(const uint4*)(xt + (((size_t)((rowbase + yi1)*Wn + xi0)) << 7) + cb);
        const uint4 q3 = *(const uint4*)(xt + (((size_t)((rowbase + yi1)*Wn + xi1)) << 7) + cb);

        // ---- combine + repack to bf16 ----
        unsigned bw[4];
        const unsigned* u0 = (const unsigned*)&q0;
        const unsigned* u1 = (const unsigned*)&q1;
        const unsigned* u2 = (const unsigned*)&q2;
        const unsigned* u3 = (const unsigned*)&q3;
        #pragma unroll
        for (int q = 0; q < 4; ++q) {
            float lo = w0_*bflo(u0[q]) + w1_*bflo(u1[q]) + w2_*bflo(u2[q]) + w3_*bflo(u3[q]);
            float hi = w0_*bfhi(u0[q]) + w1_*bfhi(u1[q]) + w2_*bfhi(u2[q]) + w3_*bfhi(u3[q]);
            bw[q] = ((unsigned)(unsigned short)f2bf(hi) << 16) | (unsigned short)f2bf(lo);
        }
        int4 bi = make_int4(bw[0], bw[1], bw[2], bw[3]);
        bf16x8 bfrag = __builtin_bit_cast(bf16x8, bi);

        // ---- 8 MFMA from LDS-staged A ----
        #pragma unroll
        for (int ot = 0; ot < 8; ++ot) {
            int4 av = *(const int4*)&a_lds[cur][(ot*64 + l)*16];
            acc[ot] = __builtin_amdgcn_mfma_f32_16x16x32_bf16(
                __builtin_bit_cast(bf16x8, av), bfrag, acc[ot], 0, 0, 0);
        }
        cur ^= 1;
    }

    // ---- epilogue ----
    #pragma unroll
    for (int ot = 0; ot < 8; ++ot) {
        #pragma unroll
        for (int r = 0; r < 4; ++r) {
            int oc = ot*16 + lg*4 + r;
            out[((size_t)(b*COn + oc) << 14) + hw] = acc[ot][r] + db[oc];
        }
    }
    #undef STAGE
}

extern "C" void kernel_launch(void* const* d_in, const int* in_sizes, int n_in,
                              void* d_out, int out_size, void* d_ws, size_t ws_size,
                              hipStream_t stream) {
    const float* x  = (const float*)d_in[0];
    const float* ow = (const float*)d_in[1];
    const float* ob = (const float*)d_in[2];
    const float* dw = (const float*)d_in[3];
    const float* db = (const float*)d_in[4];
    float* out  = (float*)d_out;

    // workspace layout (24.2 MB total)
    float*          offs = (float*)d_ws;                            // 7,077,888 B
    short*          pw   = (short*)((char*)d_ws + 7077888);         //   294,912 B
    short*          pwo  = (short*)((char*)d_ws + 7372800);         //    73,728 B
    unsigned short* xtp  = (unsigned short*)((char*)d_ws + 7446528);// 16,777,216 B

    hipLaunchKernelGGL(k_transpose,   dim3(Bn*Hn),    dim3(256), 0, stream, x, xtp);
    hipLaunchKernelGGL(k_pack_w,      dim3(288),      dim3(64),  0, stream, dw, pw);
    hipLaunchKernelGGL(k_pack_ow,     dim3(72),       dim3(64),  0, stream, ow, pwo);
    hipLaunchKernelGGL(k_offset_mfma, dim3(NPIX/64),  dim3(256), 0, stream, xtp, pwo, ob, offs);
    hipLaunchKernelGGL(k_deform_mfma, dim3(NPIX/64),  dim3(256), 0, stream,
                       xtp, (const char*)pw, db, offs, out);
}